// Round 16
// baseline (653.863 us; speedup 1.0000x reference)
//
#include <hip/hip_runtime.h>

#define NN 100000
#define NP 100096   // padded rows (782 blocks * 128)
#define NE 1000000
#define NG 1000
#define H 128
#define NLAYER 4
#define NEG 0.2f
#define SCAN_BLOCKS 98
#define NCHUNK 8
#define CHUNKSZ ((NN + NCHUNK - 1) / NCHUNK)   // 12500
#define NB4 ((NE / 4 + 255) / 256)             // 977

using short8 = __attribute__((ext_vector_type(8))) short;
using fx4 = __attribute__((ext_vector_type(4))) float;

__device__ __forceinline__ float lrelu(float x) { return x >= 0.f ? x : NEG * x; }

__device__ __forceinline__ unsigned short f2bf(float f) {
    union { float f; unsigned int u; } v;
    v.f = f;
    return (unsigned short)((v.u + 0x7fffu + ((v.u >> 16) & 1u)) >> 16);
}
__device__ __forceinline__ float bflo(unsigned int u) {
    union { unsigned int x; float f; } v;
    v.x = u << 16;
    return v.f;
}
__device__ __forceinline__ float bfhi(unsigned int u) {
    union { unsigned int x; float f; } v;
    v.x = u & 0xffff0000u;
    return v.f;
}

// ---------------- Weight prep ----------------
__global__ __launch_bounds__(256) void k_wt(const float* __restrict__ Wq,
                                            const float* __restrict__ Wk,
                                            const float* __restrict__ Wr,
                                            unsigned short* __restrict__ WT) {
    int mat = blockIdx.x;
    int l = mat / 3;
    int kind = mat - l * 3;
    const float* src = (kind == 0 ? Wq : kind == 1 ? Wk : Wr) + (size_t)l * H * H;
    unsigned short* dst = WT + (size_t)mat * H * H;
    for (int idx = threadIdx.x; idx < H * H; idx += 256) {
        int kk = idx >> 7, n = idx & 127;
        dst[n * H + kk] = f2bf(src[idx]);
    }
}

// ---------------- CSR build (XCD-partitioned hist + scatter) ----------------
__global__ __launch_bounds__(256) void k_hist(const int* __restrict__ dst, int* __restrict__ deg) {
    int chunk = blockIdx.x & 7;
    int blk = blockIdx.x >> 3;
    int i = blk * 256 + threadIdx.x;
    if (i * 4 >= NE) return;
    int lo = chunk * CHUNKSZ, hi = lo + CHUNKSZ;
    int4 d = *(const int4*)(dst + i * 4);
    if (d.x >= lo && d.x < hi) atomicAdd(&deg[d.x], 1);
    if (d.y >= lo && d.y < hi) atomicAdd(&deg[d.y], 1);
    if (d.z >= lo && d.z < hi) atomicAdd(&deg[d.z], 1);
    if (d.w >= lo && d.w < hi) atomicAdd(&deg[d.w], 1);
}

__global__ __launch_bounds__(1024) void k_scan1(const int* __restrict__ deg,
                                                int* __restrict__ rowp,
                                                int* __restrict__ bsum) {
    __shared__ int tmp[1024];
    int t = threadIdx.x;
    int i = blockIdx.x * 1024 + t;
    int v = (i < NN) ? deg[i] : 0;
    tmp[t] = v;
    __syncthreads();
    for (int off = 1; off < 1024; off <<= 1) {
        int u = (t >= off) ? tmp[t - off] : 0;
        __syncthreads();
        tmp[t] += u;
        __syncthreads();
    }
    if (i < NN) rowp[i] = tmp[t] - v;
    if (t == 1023) bsum[blockIdx.x] = tmp[1023];
}

__global__ __launch_bounds__(128) void k_scan2(int* __restrict__ bsum) {
    __shared__ int tmp[128];
    int t = threadIdx.x;
    int v = (t < SCAN_BLOCKS) ? bsum[t] : 0;
    tmp[t] = v;
    __syncthreads();
    for (int off = 1; off < 128; off <<= 1) {
        int u = (t >= off) ? tmp[t - off] : 0;
        __syncthreads();
        tmp[t] += u;
        __syncthreads();
    }
    if (t < SCAN_BLOCKS) bsum[t] = tmp[t] - v;
}

#define SCAN3_BLOCKS ((NN + 255) / 256)
__global__ __launch_bounds__(256) void k_scan3g(const int* __restrict__ bsum,
                                                int* __restrict__ rowp,
                                                int* __restrict__ cursor,
                                                const int* __restrict__ gid,
                                                int* __restrict__ gstart) {
    int bid = blockIdx.x;
    int t = threadIdx.x;
    if (bid < SCAN3_BLOCKS) {
        int i = bid * 256 + t;
        if (i < NN) {
            int v = rowp[i] + bsum[i >> 10];
            rowp[i] = v;
            cursor[i] = v;
        }
        if (i == 0) rowp[NN] = NE;
    } else {
        int g = (bid - SCAN3_BLOCKS) * 256 + t;
        if (g > NG) return;
        if (g == NG) { gstart[NG] = NN; return; }
        int lo = 0, hi = NN;
        while (lo < hi) {
            int mid = (lo + hi) >> 1;
            if (gid[mid] < g) lo = mid + 1; else hi = mid;
        }
        gstart[g] = lo;
    }
}

__global__ __launch_bounds__(256) void k_scatter(const int* __restrict__ src,
                                                 const int* __restrict__ dst,
                                                 int* __restrict__ cursor,
                                                 int* __restrict__ csr_src) {
    int chunk = blockIdx.x & 7;
    int blk = blockIdx.x >> 3;
    int i = blk * 256 + threadIdx.x;
    if (i * 4 >= NE) return;
    int lo = chunk * CHUNKSZ, hi = lo + CHUNKSZ;
    int4 s = *(const int4*)(src + i * 4);
    int4 d = *(const int4*)(dst + i * 4);
    if (d.x >= lo && d.x < hi) csr_src[atomicAdd(&cursor[d.x], 1)] = s.x;
    if (d.y >= lo && d.y < hi) csr_src[atomicAdd(&cursor[d.y], 1)] = s.y;
    if (d.z >= lo && d.z < hi) csr_src[atomicAdd(&cursor[d.z], 1)] = s.z;
    if (d.w >= lo && d.w < hi) csr_src[atomicAdd(&cursor[d.w], 1)] = s.w;
}

// ---------------- FUSED atom encoder + layer-0 q/k GEMM ----------------
// launch_bounds(256,4): LDS caps at 4 blocks/CU anyway; raise VGPR budget to 128
// so the 18 encode loads stay in flight. Encode: batch-load then accumulate
// (per-channel f-order unchanged -> bit-exact).
__global__ __launch_bounds__(256, 4) void k_aqk_mfma(const int* __restrict__ nfeats,
                                                     const float* __restrict__ emb,
                                                     const unsigned short* __restrict__ WTq,
                                                     const float* __restrict__ bq,
                                                     const unsigned short* __restrict__ WTk,
                                                     const float* __restrict__ bk,
                                                     unsigned short* __restrict__ q,
                                                     unsigned short* __restrict__ k) {
    __shared__ unsigned short hls[4][32][136];
    __shared__ int nf[128 * 9];
    int t = threadIdx.x;
    int lane = t & 63;
    int wave = t >> 6;
    int row0 = blockIdx.x * 128 + wave * 32;
    int lrow = lane & 15;
    int lk = (lane >> 4) << 3;
    unsigned short (*S)[136] = hls[wave];

    {
        int gbase = blockIdx.x * 128 * 9;
        for (int i = t; i < 128 * 9; i += 256) {
            int gi = gbase + i;
            nf[i] = nfeats[gi < NN * 9 ? gi : NN * 9 - 1];
        }
    }
    __syncthreads();

    // ---- atom encode: half-wave per row, float4 channels, batch-load 18 then sum ----
    {
        int half = lane >> 5;         // 0: row rr, 1: row rr+1
        int c4 = (lane & 31) * 4;     // 4 channels per lane
        const int* nfw = nf + wave * 32 * 9;
        for (int rr = 0; rr < 32; rr += 4) {
            int rA = rr + half;
            int rB = rr + 2 + half;
            float4 eA[9], eB[9];
#pragma unroll
            for (int f = 0; f < 9; ++f) {
                int iA = nfw[rA * 9 + f];
                int iB = nfw[rB * 9 + f];
                eA[f] = *(const float4*)(emb + (size_t)((f << 6) + iA) * H + c4);
                eB[f] = *(const float4*)(emb + (size_t)((f << 6) + iB) * H + c4);
            }
            float sA0 = 0.f, sA1 = 0.f, sA2 = 0.f, sA3 = 0.f;
            float sB0 = 0.f, sB1 = 0.f, sB2 = 0.f, sB3 = 0.f;
#pragma unroll
            for (int f = 0; f < 9; ++f) {
                sA0 += eA[f].x; sA1 += eA[f].y; sA2 += eA[f].z; sA3 += eA[f].w;
                sB0 += eB[f].x; sB1 += eB[f].y; sB2 += eB[f].z; sB3 += eB[f].w;
            }
            uint2 pA, pB;
            pA.x = (unsigned int)f2bf(sA0) | ((unsigned int)f2bf(sA1) << 16);
            pA.y = (unsigned int)f2bf(sA2) | ((unsigned int)f2bf(sA3) << 16);
            pB.x = (unsigned int)f2bf(sB0) | ((unsigned int)f2bf(sB1) << 16);
            pB.y = (unsigned int)f2bf(sB2) | ((unsigned int)f2bf(sB3) << 16);
            *(uint2*)&S[rA][c4] = pA;
            *(uint2*)&S[rB][c4] = pB;
        }
    }

    short8 a[2][4];
#pragma unroll
    for (int rt = 0; rt < 2; ++rt)
#pragma unroll
        for (int ks = 0; ks < 4; ++ks)
            a[rt][ks] = *(const short8*)&S[rt * 16 + lrow][ks * 32 + lk];

#pragma unroll
    for (int pass = 0; pass < 4; ++pass) {
        const unsigned short* W = (pass < 2) ? WTq : WTk;
        const float* b = (pass < 2) ? bq : bk;
        unsigned short* o = (pass < 2) ? q : k;
        int c0 = (pass & 1) * 4;
        fx4 acc[2][4];
#pragma unroll
        for (int ct = 0; ct < 4; ++ct) {
            float v = b[(c0 + ct) * 16 + lrow];
#pragma unroll
            for (int rt = 0; rt < 2; ++rt) acc[rt][ct] = fx4{v, v, v, v};
        }
#pragma unroll
        for (int ks = 0; ks < 4; ++ks)
#pragma unroll
            for (int ct = 0; ct < 4; ++ct) {
                short8 w = *(const short8*)(W + ((c0 + ct) * 16 + lrow) * H + ks * 32 + lk);
#pragma unroll
                for (int rt = 0; rt < 2; ++rt)
                    acc[rt][ct] = __builtin_amdgcn_mfma_f32_16x16x32_bf16(a[rt][ks], w, acc[rt][ct], 0, 0, 0);
            }
#pragma unroll
        for (int rt = 0; rt < 2; ++rt)
#pragma unroll
            for (int ct = 0; ct < 4; ++ct)
#pragma unroll
                for (int rg = 0; rg < 4; ++rg)
                    S[rt * 16 + ((lane >> 4) << 2) + rg][(c0 + ct) * 16 + lrow] = f2bf(acc[rt][ct][rg]);
#pragma unroll
        for (int step = 0; step < 4; ++step) {
            int cch = step * 64 + lane;
            int r = cch >> 3;
            int off = c0 * 16 + (cch & 7) * 8;
            int gr = row0 + r;
            if (gr < NN)
                *(uint4*)(o + (size_t)gr * H + off) = *(const uint4*)&S[r][off];
        }
    }
}

// ---------------- h_new = lrelu(agg@Wr + br) (final layer), LDS-staged stores ----------------
__global__ __launch_bounds__(256, 4) void k_r_mfma(const unsigned short* __restrict__ agg,
                                                   const unsigned short* __restrict__ WTr,
                                                   const float* __restrict__ br,
                                                   unsigned short* __restrict__ hout) {
    __shared__ unsigned short hls[4][32][136];
    int lane = threadIdx.x & 63;
    int wave = threadIdx.x >> 6;
    int row0 = blockIdx.x * 128 + wave * 32;
    int lrow = lane & 15;
    int lk = (lane >> 4) << 3;
    unsigned short (*S)[136] = hls[wave];

    short8 a[2][4];
#pragma unroll
    for (int rt = 0; rt < 2; ++rt)
#pragma unroll
        for (int ks = 0; ks < 4; ++ks)
            a[rt][ks] = *(const short8*)(agg + (size_t)(row0 + rt * 16 + lrow) * H + ks * 32 + lk);

#pragma unroll
    for (int chf = 0; chf < 2; ++chf) {
        int c0 = chf * 4;
        fx4 acc[2][4];
#pragma unroll
        for (int ct = 0; ct < 4; ++ct) {
            float v = br[(c0 + ct) * 16 + lrow];
#pragma unroll
            for (int rt = 0; rt < 2; ++rt) acc[rt][ct] = fx4{v, v, v, v};
        }
#pragma unroll
        for (int ks = 0; ks < 4; ++ks)
#pragma unroll
            for (int ct = 0; ct < 4; ++ct) {
                short8 w = *(const short8*)(WTr + ((c0 + ct) * 16 + lrow) * H + ks * 32 + lk);
#pragma unroll
                for (int rt = 0; rt < 2; ++rt)
                    acc[rt][ct] = __builtin_amdgcn_mfma_f32_16x16x32_bf16(a[rt][ks], w, acc[rt][ct], 0, 0, 0);
            }
#pragma unroll
        for (int rt = 0; rt < 2; ++rt)
#pragma unroll
            for (int ct = 0; ct < 4; ++ct)
#pragma unroll
                for (int rg = 0; rg < 4; ++rg)
                    S[rt * 16 + ((lane >> 4) << 2) + rg][(c0 + ct) * 16 + lrow] = f2bf(lrelu(acc[rt][ct][rg]));
    }
#pragma unroll
    for (int step = 0; step < 8; ++step) {
        int cch = step * 64 + lane;
        int r = cch >> 4;
        int off = (cch & 15) * 8;
        int gr = row0 + r;
        if (gr < NN)
            *(uint4*)(hout + (size_t)gr * H + off) = *(const uint4*)&S[r][off];
    }
}

// ---------------- FUSED: h_new = lrelu(agg@Wr+br); q = h_new@Wq+bq; k = h_new@Wk+bk ----------------
__global__ __launch_bounds__(256, 4) void k_rqk_mfma(const unsigned short* __restrict__ agg,
                                                     const unsigned short* __restrict__ WTr,
                                                     const float* __restrict__ br,
                                                     const unsigned short* __restrict__ WTq,
                                                     const float* __restrict__ bq,
                                                     const unsigned short* __restrict__ WTk,
                                                     const float* __restrict__ bk,
                                                     unsigned short* __restrict__ q,
                                                     unsigned short* __restrict__ k) {
    __shared__ unsigned short hls[4][32][136];
    int lane = threadIdx.x & 63;
    int wave = threadIdx.x >> 6;
    int row0 = blockIdx.x * 128 + wave * 32;
    int lrow = lane & 15;
    int lk = (lane >> 4) << 3;
    unsigned short (*S)[136] = hls[wave];

    short8 a[2][4];
#pragma unroll
    for (int rt = 0; rt < 2; ++rt)
#pragma unroll
        for (int ks = 0; ks < 4; ++ks)
            a[rt][ks] = *(const short8*)(agg + (size_t)(row0 + rt * 16 + lrow) * H + ks * 32 + lk);

#pragma unroll
    for (int chf = 0; chf < 2; ++chf) {
        int c0 = chf * 4;
        fx4 acc[2][4];
#pragma unroll
        for (int ct = 0; ct < 4; ++ct) {
            float v = br[(c0 + ct) * 16 + lrow];
#pragma unroll
            for (int rt = 0; rt < 2; ++rt) acc[rt][ct] = fx4{v, v, v, v};
        }
#pragma unroll
        for (int ks = 0; ks < 4; ++ks)
#pragma unroll
            for (int ct = 0; ct < 4; ++ct) {
                short8 w = *(const short8*)(WTr + ((c0 + ct) * 16 + lrow) * H + ks * 32 + lk);
#pragma unroll
                for (int rt = 0; rt < 2; ++rt)
                    acc[rt][ct] = __builtin_amdgcn_mfma_f32_16x16x32_bf16(a[rt][ks], w, acc[rt][ct], 0, 0, 0);
            }
#pragma unroll
        for (int rt = 0; rt < 2; ++rt)
#pragma unroll
            for (int ct = 0; ct < 4; ++ct)
#pragma unroll
                for (int rg = 0; rg < 4; ++rg)
                    S[rt * 16 + ((lane >> 4) << 2) + rg][(c0 + ct) * 16 + lrow] = f2bf(lrelu(acc[rt][ct][rg]));
    }

    short8 a2[2][4];
#pragma unroll
    for (int rt = 0; rt < 2; ++rt)
#pragma unroll
        for (int ks = 0; ks < 4; ++ks)
            a2[rt][ks] = *(const short8*)&S[rt * 16 + lrow][ks * 32 + lk];

#pragma unroll
    for (int pass = 0; pass < 4; ++pass) {
        const unsigned short* W = (pass < 2) ? WTq : WTk;
        const float* b = (pass < 2) ? bq : bk;
        unsigned short* o = (pass < 2) ? q : k;
        int c0 = (pass & 1) * 4;
        fx4 acc[2][4];
#pragma unroll
        for (int ct = 0; ct < 4; ++ct) {
            float v = b[(c0 + ct) * 16 + lrow];
#pragma unroll
            for (int rt = 0; rt < 2; ++rt) acc[rt][ct] = fx4{v, v, v, v};
        }
#pragma unroll
        for (int ks = 0; ks < 4; ++ks)
#pragma unroll
            for (int ct = 0; ct < 4; ++ct) {
                short8 w = *(const short8*)(W + ((c0 + ct) * 16 + lrow) * H + ks * 32 + lk);
#pragma unroll
                for (int rt = 0; rt < 2; ++rt)
                    acc[rt][ct] = __builtin_amdgcn_mfma_f32_16x16x32_bf16(a2[rt][ks], w, acc[rt][ct], 0, 0, 0);
            }
#pragma unroll
        for (int rt = 0; rt < 2; ++rt)
#pragma unroll
            for (int ct = 0; ct < 4; ++ct)
#pragma unroll
                for (int rg = 0; rg < 4; ++rg)
                    S[rt * 16 + ((lane >> 4) << 2) + rg][(c0 + ct) * 16 + lrow] = f2bf(acc[rt][ct][rg]);
#pragma unroll
        for (int step = 0; step < 4; ++step) {
            int cch = step * 64 + lane;
            int r = cch >> 3;
            int off = c0 * 16 + (cch & 7) * 8;
            int gr = row0 + r;
            if (gr < NN)
                *(uint4*)(o + (size_t)gr * H + off) = *(const uint4*)&S[r][off];
        }
    }
}

// ---------------- aggregation: 16 gathers per iter group (4 in flight per lane) ----------------
__global__ __launch_bounds__(256) void k_agg(const unsigned short* __restrict__ q,
                                             const unsigned short* __restrict__ kk,
                                             const int* __restrict__ rowp,
                                             const int* __restrict__ csr_src,
                                             unsigned short* __restrict__ agg) {
    int node = blockIdx.x * 4 + (threadIdx.x >> 6);
    if (node >= NN) return;
    int lane = threadIdx.x & 63;
    int qt = lane >> 4;
    int ql = lane & 15;
    int start = rowp[node];
    int end = rowp[node + 1];

    uint4 qp = *(const uint4*)(q + (size_t)node * H + ql * 8);
    float qv0 = bflo(qp.x), qv1 = bfhi(qp.x), qv2 = bflo(qp.y), qv3 = bfhi(qp.y);
    float qv4 = bflo(qp.z), qv5 = bfhi(qp.z), qv6 = bflo(qp.w), qv7 = bfhi(qp.w);
    float a0 = 0.f, a1 = 0.f, a2 = 0.f, a3 = 0.f, a4 = 0.f, a5 = 0.f, a6 = 0.f, a7 = 0.f;

    for (int base = start; base < end; base += 64) {
        int cnt = end - base;
        if (cnt > 64) cnt = 64;
        int sid = (lane < cnt) ? csr_src[base + lane] : 0;
        int cnt16 = (cnt + 15) & ~15;
        for (int j = 0; j < cnt16; j += 16) {
            int jj0 = j + qt;
            int jj1 = j + 4 + qt;
            int jj2 = j + 8 + qt;
            int jj3 = j + 12 + qt;
            int s0 = __shfl(sid, jj0);
            int s1 = __shfl(sid, jj1);
            int s2 = __shfl(sid, jj2);
            int s3 = __shfl(sid, jj3);
            uint4 kp0 = *(const uint4*)(kk + (size_t)s0 * H + ql * 8);
            uint4 kp1 = *(const uint4*)(kk + (size_t)s1 * H + ql * 8);
            uint4 kp2 = *(const uint4*)(kk + (size_t)s2 * H + ql * 8);
            uint4 kp3 = *(const uint4*)(kk + (size_t)s3 * H + ql * 8);
            if (jj0 < cnt) {
                a0 += lrelu(qv0 + bflo(kp0.x)); a1 += lrelu(qv1 + bfhi(kp0.x));
                a2 += lrelu(qv2 + bflo(kp0.y)); a3 += lrelu(qv3 + bfhi(kp0.y));
                a4 += lrelu(qv4 + bflo(kp0.z)); a5 += lrelu(qv5 + bfhi(kp0.z));
                a6 += lrelu(qv6 + bflo(kp0.w)); a7 += lrelu(qv7 + bfhi(kp0.w));
            }
            if (jj1 < cnt) {
                a0 += lrelu(qv0 + bflo(kp1.x)); a1 += lrelu(qv1 + bfhi(kp1.x));
                a2 += lrelu(qv2 + bflo(kp1.y)); a3 += lrelu(qv3 + bfhi(kp1.y));
                a4 += lrelu(qv4 + bflo(kp1.z)); a5 += lrelu(qv5 + bfhi(kp1.z));
                a6 += lrelu(qv6 + bflo(kp1.w)); a7 += lrelu(qv7 + bfhi(kp1.w));
            }
            if (jj2 < cnt) {
                a0 += lrelu(qv0 + bflo(kp2.x)); a1 += lrelu(qv1 + bfhi(kp2.x));
                a2 += lrelu(qv2 + bflo(kp2.y)); a3 += lrelu(qv3 + bfhi(kp2.y));
                a4 += lrelu(qv4 + bflo(kp2.z)); a5 += lrelu(qv5 + bfhi(kp2.z));
                a6 += lrelu(qv6 + bflo(kp2.w)); a7 += lrelu(qv7 + bfhi(kp2.w));
            }
            if (jj3 < cnt) {
                a0 += lrelu(qv0 + bflo(kp3.x)); a1 += lrelu(qv1 + bfhi(kp3.x));
                a2 += lrelu(qv2 + bflo(kp3.y)); a3 += lrelu(qv3 + bfhi(kp3.y));
                a4 += lrelu(qv4 + bflo(kp3.z)); a5 += lrelu(qv5 + bfhi(kp3.z));
                a6 += lrelu(qv6 + bflo(kp3.w)); a7 += lrelu(qv7 + bfhi(kp3.w));
            }
        }
    }
    a0 += __shfl_xor(a0, 16); a0 += __shfl_xor(a0, 32);
    a1 += __shfl_xor(a1, 16); a1 += __shfl_xor(a1, 32);
    a2 += __shfl_xor(a2, 16); a2 += __shfl_xor(a2, 32);
    a3 += __shfl_xor(a3, 16); a3 += __shfl_xor(a3, 32);
    a4 += __shfl_xor(a4, 16); a4 += __shfl_xor(a4, 32);
    a5 += __shfl_xor(a5, 16); a5 += __shfl_xor(a5, 32);
    a6 += __shfl_xor(a6, 16); a6 += __shfl_xor(a6, 32);
    a7 += __shfl_xor(a7, 16); a7 += __shfl_xor(a7, 32);
    if (qt == 0) {
        uint4 o;
        o.x = (unsigned int)f2bf(a0) | ((unsigned int)f2bf(a1) << 16);
        o.y = (unsigned int)f2bf(a2) | ((unsigned int)f2bf(a3) << 16);
        o.z = (unsigned int)f2bf(a4) | ((unsigned int)f2bf(a5) << 16);
        o.w = (unsigned int)f2bf(a6) | ((unsigned int)f2bf(a7) << 16);
        *(uint4*)(agg + (size_t)node * H + ql * 8) = o;
    }
}

// ---------------- segmented graph pooling ----------------
__global__ __launch_bounds__(256) void k_pool_seg(const unsigned short* __restrict__ h,
                                                  const int* __restrict__ gstart,
                                                  float* __restrict__ hg) {
    int g = blockIdx.x * 4 + (threadIdx.x >> 6);
    if (g >= NG) return;
    int lane = threadIdx.x & 63;
    int s = gstart[g], e = gstart[g + 1];
    float ax = 0.f, ay = 0.f;
    for (int n = s; n < e; ++n) {
        unsigned int hp = *(const unsigned int*)(h + (size_t)n * H + lane * 2);
        ax += bflo(hp);
        ay += bfhi(hp);
    }
    float2 o;
    o.x = ax;
    o.y = ay;
    *(float2*)(hg + (size_t)g * H + lane * 2) = o;
}

// ---------------- MLP head ----------------
__global__ __launch_bounds__(256) void k_mlp1(const float* __restrict__ hg,
                                              const float* __restrict__ W1,
                                              const float* __restrict__ b1,
                                              float* __restrict__ x1) {
    __shared__ float W1s[128 * 64];
    __shared__ float hgs[4 * 128];
    int t = threadIdx.x;
    int g0 = blockIdx.x * 4;
#pragma unroll
    for (int i = 0; i < 32; ++i) W1s[t + i * 256] = W1[t + i * 256];
    for (int i = t; i < 4 * 128; i += 256) hgs[i] = hg[(size_t)g0 * H + i];
    __syncthreads();
    int g = t >> 6, c = t & 63;
    float acc = b1[c];
    const float* row = hgs + g * 128;
    for (int j = 0; j < 128; ++j) acc += row[j] * W1s[j * 64 + c];
    x1[(g0 + g) * 64 + c] = acc;
}

template <int C>
__global__ __launch_bounds__(1024) void k_bnstats(const float* __restrict__ x,
                                                  float* __restrict__ stats) {
    __shared__ float red[1024];
    __shared__ float mus[C];
    int t = threadIdx.x;
    int c = t & (C - 1), rc = t / C;
    const int R = 1024 / C;
    float s = 0.f;
    for (int g = rc; g < NG; g += R) s += x[g * C + c];
    red[t] = s;
    __syncthreads();
    if (t < C) {
        float S = 0.f;
        for (int i = 0; i < R; ++i) S += red[i * C + t];
        float mu = S / NG;
        mus[t] = mu;
        stats[t] = mu;
    }
    __syncthreads();
    float mu = mus[c];
    float s2 = 0.f;
    for (int g = rc; g < NG; g += R) {
        float d = x[g * C + c] - mu;
        s2 += d * d;
    }
    red[t] = s2;
    __syncthreads();
    if (t < C) {
        float Q = 0.f;
        for (int i = 0; i < R; ++i) Q += red[i * C + t];
        stats[C + t] = rsqrtf(Q / NG + 1e-5f);
    }
}

__global__ __launch_bounds__(256) void k_mlp2f(const float* __restrict__ x1,
                                               const float* __restrict__ st,
                                               const float* __restrict__ g1,
                                               const float* __restrict__ be1,
                                               const float* __restrict__ W2,
                                               const float* __restrict__ b2,
                                               float* __restrict__ x2) {
    __shared__ float W2s[64 * 32];
    __shared__ float x1s[8 * 64];
    int t = threadIdx.x;
    int g0 = blockIdx.x * 8;
#pragma unroll
    for (int i = 0; i < 8; ++i) W2s[t + i * 256] = W2[t + i * 256];
#pragma unroll
    for (int i = 0; i < 2; ++i) {
        int idx = t + i * 256;
        int c = idx & 63;
        float v = x1[(size_t)g0 * 64 + idx];
        v = (v - st[c]) * st[64 + c] * g1[c] + be1[c];
        x1s[idx] = lrelu(v);
    }
    __syncthreads();
    int g = t >> 5, c = t & 31;
    float acc = b2[c];
    const float* row = x1s + g * 64;
    for (int j = 0; j < 64; ++j) acc += row[j] * W2s[j * 32 + c];
    x2[(g0 + g) * 32 + c] = acc;
}

__global__ __launch_bounds__(256) void k_mlp3f(const float* __restrict__ x2,
                                               const float* __restrict__ st,
                                               const float* __restrict__ g2,
                                               const float* __restrict__ be2,
                                               const float* __restrict__ W3,
                                               const float* __restrict__ b3,
                                               float* __restrict__ out) {
    int g = blockIdx.x * blockDim.x + threadIdx.x;
    if (g >= NG) return;
    float acc = b3[0];
    for (int j = 0; j < 32; ++j) {
        float v = (x2[g * 32 + j] - st[j]) * st[32 + j] * g2[j] + be2[j];
        acc += lrelu(v) * W3[j];
    }
    out[g] = acc;
}

extern "C" void kernel_launch(void* const* d_in, const int* in_sizes, int n_in,
                              void* d_out, int out_size, void* d_ws, size_t ws_size,
                              hipStream_t stream) {
    const int* nfeats = (const int*)d_in[0];
    const int* src = (const int*)d_in[2];
    const int* dst = (const int*)d_in[3];
    const int* gid = (const int*)d_in[4];
    const float* emb = (const float*)d_in[5];
    const float* Wq = (const float*)d_in[6];
    const float* bq = (const float*)d_in[7];
    const float* Wk = (const float*)d_in[8];
    const float* bk = (const float*)d_in[9];
    const float* Wr = (const float*)d_in[10];
    const float* br = (const float*)d_in[11];
    const float* W1 = (const float*)d_in[12];
    const float* b1 = (const float*)d_in[13];
    const float* g1 = (const float*)d_in[14];
    const float* be1 = (const float*)d_in[15];
    const float* W2 = (const float*)d_in[16];
    const float* b2 = (const float*)d_in[17];
    const float* g2 = (const float*)d_in[18];
    const float* be2 = (const float*)d_in[19];
    const float* W3 = (const float*)d_in[20];
    const float* b3 = (const float*)d_in[21];
    float* out = (float*)d_out;

    size_t nh = (size_t)NP * H;
    unsigned short* P0 = (unsigned short*)d_ws;
    unsigned short* P1 = P0 + nh;
    unsigned short* P2 = P1 + nh;
    unsigned short* WT = P2 + nh;
    float* hg = (float*)(WT + 12 * H * H);
    float* x1 = hg + (size_t)NG * H;
    float* x2 = x1 + (size_t)NG * 64;
    float* st = x2 + (size_t)NG * 32;
    int* cursor = (int*)(st + 2 * 64);
    int* rowp = cursor + NN;
    int* bsum = rowp + NN + 1;
    int* csr_src = bsum + 128;
    int* gstart = csr_src + NE;

    // ---- CSR build + graph boundaries (XCD-partitioned hist/scatter) ----
    hipMemsetAsync(cursor, 0, NN * sizeof(int), stream);
    k_hist<<<NB4 * NCHUNK, 256, 0, stream>>>(dst, cursor);
    k_scan1<<<SCAN_BLOCKS, 1024, 0, stream>>>(cursor, rowp, bsum);
    k_scan2<<<1, 128, 0, stream>>>(bsum);
    k_scan3g<<<SCAN3_BLOCKS + 4, 256, 0, stream>>>(bsum, rowp, cursor, gid, gstart);
    k_scatter<<<NB4 * NCHUNK, 256, 0, stream>>>(src, dst, cursor, csr_src);

    // ---- weight prep ----
    k_wt<<<12, 256, 0, stream>>>(Wq, Wk, Wr, WT);

    const int NB = NP / 128;  // 782
    k_aqk_mfma<<<NB, 256, 0, stream>>>(nfeats, emb, WT + 0 * H * H, bq, WT + 1 * H * H, bk, P1, P2);
    for (int l = 0; l < NLAYER; ++l) {
        k_agg<<<(NN + 3) / 4, 256, 0, stream>>>(P1, P2, rowp, csr_src, P0);
        if (l < NLAYER - 1) {
            k_rqk_mfma<<<NB, 256, 0, stream>>>(P0, WT + (size_t)(l * 3 + 2) * H * H, br + l * H,
                                               WT + (size_t)((l + 1) * 3 + 0) * H * H, bq + (l + 1) * H,
                                               WT + (size_t)((l + 1) * 3 + 1) * H * H, bk + (l + 1) * H,
                                               P1, P2);
        } else {
            k_r_mfma<<<NB, 256, 0, stream>>>(P0, WT + (size_t)(l * 3 + 2) * H * H, br + l * H, P1);
        }
    }

    k_pool_seg<<<(NG + 3) / 4, 256, 0, stream>>>(P1, gstart, hg);

    // ---- MLP head ----
    k_mlp1<<<NG / 4, 256, 0, stream>>>(hg, W1, b1, x1);
    k_bnstats<64><<<1, 1024, 0, stream>>>(x1, st);
    k_mlp2f<<<NG / 8, 256, 0, stream>>>(x1, st, g1, be1, W2, b2, x2);
    k_bnstats<32><<<1, 1024, 0, stream>>>(x2, st);
    k_mlp3f<<<(NG + 255) / 256, 256, 0, stream>>>(x2, st, g2, be2, W3, b3, out);
}

// Round 17
// 629.255 us; speedup vs baseline: 1.0391x; 1.0391x over previous
//
#include <hip/hip_runtime.h>

#define NN 100000
#define NP 100096   // padded rows (782 blocks * 128)
#define NE 1000000
#define NG 1000
#define H 128
#define NLAYER 4
#define NEG 0.2f
#define SCAN_BLOCKS 98
#define NCHUNK 8
#define CHUNKSZ ((NN + NCHUNK - 1) / NCHUNK)   // 12500
#define NB4 ((NE / 4 + 255) / 256)             // 977

using short8 = __attribute__((ext_vector_type(8))) short;
using fx4 = __attribute__((ext_vector_type(4))) float;

__device__ __forceinline__ float lrelu(float x) { return x >= 0.f ? x : NEG * x; }

__device__ __forceinline__ unsigned short f2bf(float f) {
    union { float f; unsigned int u; } v;
    v.f = f;
    return (unsigned short)((v.u + 0x7fffu + ((v.u >> 16) & 1u)) >> 16);
}
__device__ __forceinline__ float bflo(unsigned int u) {
    union { unsigned int x; float f; } v;
    v.x = u << 16;
    return v.f;
}
__device__ __forceinline__ float bfhi(unsigned int u) {
    union { unsigned int x; float f; } v;
    v.x = u & 0xffff0000u;
    return v.f;
}

// ---------------- Weight prep ----------------
__global__ __launch_bounds__(256) void k_wt(const float* __restrict__ Wq,
                                            const float* __restrict__ Wk,
                                            const float* __restrict__ Wr,
                                            unsigned short* __restrict__ WT) {
    int mat = blockIdx.x;
    int l = mat / 3;
    int kind = mat - l * 3;
    const float* src = (kind == 0 ? Wq : kind == 1 ? Wk : Wr) + (size_t)l * H * H;
    unsigned short* dst = WT + (size_t)mat * H * H;
    for (int idx = threadIdx.x; idx < H * H; idx += 256) {
        int kk = idx >> 7, n = idx & 127;
        dst[n * H + kk] = f2bf(src[idx]);
    }
}

// ---------------- CSR build (XCD-partitioned hist + scatter) ----------------
__global__ __launch_bounds__(256) void k_hist(const int* __restrict__ dst, int* __restrict__ deg) {
    int chunk = blockIdx.x & 7;
    int blk = blockIdx.x >> 3;
    int i = blk * 256 + threadIdx.x;
    if (i * 4 >= NE) return;
    int lo = chunk * CHUNKSZ, hi = lo + CHUNKSZ;
    int4 d = *(const int4*)(dst + i * 4);
    if (d.x >= lo && d.x < hi) atomicAdd(&deg[d.x], 1);
    if (d.y >= lo && d.y < hi) atomicAdd(&deg[d.y], 1);
    if (d.z >= lo && d.z < hi) atomicAdd(&deg[d.z], 1);
    if (d.w >= lo && d.w < hi) atomicAdd(&deg[d.w], 1);
}

__global__ __launch_bounds__(1024) void k_scan1(const int* __restrict__ deg,
                                                int* __restrict__ rowp,
                                                int* __restrict__ bsum) {
    __shared__ int tmp[1024];
    int t = threadIdx.x;
    int i = blockIdx.x * 1024 + t;
    int v = (i < NN) ? deg[i] : 0;
    tmp[t] = v;
    __syncthreads();
    for (int off = 1; off < 1024; off <<= 1) {
        int u = (t >= off) ? tmp[t - off] : 0;
        __syncthreads();
        tmp[t] += u;
        __syncthreads();
    }
    if (i < NN) rowp[i] = tmp[t] - v;
    if (t == 1023) bsum[blockIdx.x] = tmp[1023];
}

__global__ __launch_bounds__(128) void k_scan2(int* __restrict__ bsum) {
    __shared__ int tmp[128];
    int t = threadIdx.x;
    int v = (t < SCAN_BLOCKS) ? bsum[t] : 0;
    tmp[t] = v;
    __syncthreads();
    for (int off = 1; off < 128; off <<= 1) {
        int u = (t >= off) ? tmp[t - off] : 0;
        __syncthreads();
        tmp[t] += u;
        __syncthreads();
    }
    if (t < SCAN_BLOCKS) bsum[t] = tmp[t] - v;
}

#define SCAN3_BLOCKS ((NN + 255) / 256)
__global__ __launch_bounds__(256) void k_scan3g(const int* __restrict__ bsum,
                                                int* __restrict__ rowp,
                                                int* __restrict__ cursor,
                                                const int* __restrict__ gid,
                                                int* __restrict__ gstart) {
    int bid = blockIdx.x;
    int t = threadIdx.x;
    if (bid < SCAN3_BLOCKS) {
        int i = bid * 256 + t;
        if (i < NN) {
            int v = rowp[i] + bsum[i >> 10];
            rowp[i] = v;
            cursor[i] = v;
        }
        if (i == 0) rowp[NN] = NE;
    } else {
        int g = (bid - SCAN3_BLOCKS) * 256 + t;
        if (g > NG) return;
        if (g == NG) { gstart[NG] = NN; return; }
        int lo = 0, hi = NN;
        while (lo < hi) {
            int mid = (lo + hi) >> 1;
            if (gid[mid] < g) lo = mid + 1; else hi = mid;
        }
        gstart[g] = lo;
    }
}

__global__ __launch_bounds__(256) void k_scatter(const int* __restrict__ src,
                                                 const int* __restrict__ dst,
                                                 int* __restrict__ cursor,
                                                 int* __restrict__ csr_src) {
    int chunk = blockIdx.x & 7;
    int blk = blockIdx.x >> 3;
    int i = blk * 256 + threadIdx.x;
    if (i * 4 >= NE) return;
    int lo = chunk * CHUNKSZ, hi = lo + CHUNKSZ;
    int4 s = *(const int4*)(src + i * 4);
    int4 d = *(const int4*)(dst + i * 4);
    if (d.x >= lo && d.x < hi) csr_src[atomicAdd(&cursor[d.x], 1)] = s.x;
    if (d.y >= lo && d.y < hi) csr_src[atomicAdd(&cursor[d.y], 1)] = s.y;
    if (d.z >= lo && d.z < hi) csr_src[atomicAdd(&cursor[d.z], 1)] = s.z;
    if (d.w >= lo && d.w < hi) csr_src[atomicAdd(&cursor[d.w], 1)] = s.w;
}

// ---------------- FUSED atom encoder + layer-0 q/k GEMM ----------------
// Encode: paired-row float4 loads (one instruction fetches 2 emb rows, 1KB),
// 4-row unroll for MLP; per-channel f-order unchanged (bit-exact).
__global__ __launch_bounds__(256) void k_aqk_mfma(const int* __restrict__ nfeats,
                                                  const float* __restrict__ emb,
                                                  const unsigned short* __restrict__ WTq,
                                                  const float* __restrict__ bq,
                                                  const unsigned short* __restrict__ WTk,
                                                  const float* __restrict__ bk,
                                                  unsigned short* __restrict__ q,
                                                  unsigned short* __restrict__ k) {
    __shared__ unsigned short hls[4][32][136];
    __shared__ int nf[128 * 9];
    int t = threadIdx.x;
    int lane = t & 63;
    int wave = t >> 6;
    int row0 = blockIdx.x * 128 + wave * 32;
    int lrow = lane & 15;
    int lk = (lane >> 4) << 3;
    unsigned short (*S)[136] = hls[wave];

    {
        int gbase = blockIdx.x * 128 * 9;
        for (int i = t; i < 128 * 9; i += 256) {
            int gi = gbase + i;
            nf[i] = nfeats[gi < NN * 9 ? gi : NN * 9 - 1];
        }
    }
    __syncthreads();

    // ---- atom encode: half-wave per row, float4 channels, 4 rows/iter ----
    {
        int half = lane >> 5;         // 0: row rr, 1: row rr+1
        int c4 = (lane & 31) * 4;     // 4 channels per lane
        const int* nfw = nf + wave * 32 * 9;
        for (int rr = 0; rr < 32; rr += 4) {
            int rA = rr + half;
            int rB = rr + 2 + half;
            float sA0 = 0.f, sA1 = 0.f, sA2 = 0.f, sA3 = 0.f;
            float sB0 = 0.f, sB1 = 0.f, sB2 = 0.f, sB3 = 0.f;
#pragma unroll
            for (int f = 0; f < 9; ++f) {
                int iA = nfw[rA * 9 + f];
                int iB = nfw[rB * 9 + f];
                float4 eA = *(const float4*)(emb + (size_t)((f << 6) + iA) * H + c4);
                float4 eB = *(const float4*)(emb + (size_t)((f << 6) + iB) * H + c4);
                sA0 += eA.x; sA1 += eA.y; sA2 += eA.z; sA3 += eA.w;
                sB0 += eB.x; sB1 += eB.y; sB2 += eB.z; sB3 += eB.w;
            }
            uint2 pA, pB;
            pA.x = (unsigned int)f2bf(sA0) | ((unsigned int)f2bf(sA1) << 16);
            pA.y = (unsigned int)f2bf(sA2) | ((unsigned int)f2bf(sA3) << 16);
            pB.x = (unsigned int)f2bf(sB0) | ((unsigned int)f2bf(sB1) << 16);
            pB.y = (unsigned int)f2bf(sB2) | ((unsigned int)f2bf(sB3) << 16);
            *(uint2*)&S[rA][c4] = pA;
            *(uint2*)&S[rB][c4] = pB;
        }
    }

    short8 a[2][4];
#pragma unroll
    for (int rt = 0; rt < 2; ++rt)
#pragma unroll
        for (int ks = 0; ks < 4; ++ks)
            a[rt][ks] = *(const short8*)&S[rt * 16 + lrow][ks * 32 + lk];

#pragma unroll
    for (int pass = 0; pass < 4; ++pass) {
        const unsigned short* W = (pass < 2) ? WTq : WTk;
        const float* b = (pass < 2) ? bq : bk;
        unsigned short* o = (pass < 2) ? q : k;
        int c0 = (pass & 1) * 4;
        fx4 acc[2][4];
#pragma unroll
        for (int ct = 0; ct < 4; ++ct) {
            float v = b[(c0 + ct) * 16 + lrow];
#pragma unroll
            for (int rt = 0; rt < 2; ++rt) acc[rt][ct] = fx4{v, v, v, v};
        }
#pragma unroll
        for (int ks = 0; ks < 4; ++ks)
#pragma unroll
            for (int ct = 0; ct < 4; ++ct) {
                short8 w = *(const short8*)(W + ((c0 + ct) * 16 + lrow) * H + ks * 32 + lk);
#pragma unroll
                for (int rt = 0; rt < 2; ++rt)
                    acc[rt][ct] = __builtin_amdgcn_mfma_f32_16x16x32_bf16(a[rt][ks], w, acc[rt][ct], 0, 0, 0);
            }
#pragma unroll
        for (int rt = 0; rt < 2; ++rt)
#pragma unroll
            for (int ct = 0; ct < 4; ++ct)
#pragma unroll
                for (int rg = 0; rg < 4; ++rg)
                    S[rt * 16 + ((lane >> 4) << 2) + rg][(c0 + ct) * 16 + lrow] = f2bf(acc[rt][ct][rg]);
#pragma unroll
        for (int step = 0; step < 4; ++step) {
            int cch = step * 64 + lane;
            int r = cch >> 3;
            int off = c0 * 16 + (cch & 7) * 8;
            int gr = row0 + r;
            if (gr < NN)
                *(uint4*)(o + (size_t)gr * H + off) = *(const uint4*)&S[r][off];
        }
    }
}

// ---------------- h_new = lrelu(agg@Wr + br) (final layer), LDS-staged stores ----------------
__global__ __launch_bounds__(256) void k_r_mfma(const unsigned short* __restrict__ agg,
                                                const unsigned short* __restrict__ WTr,
                                                const float* __restrict__ br,
                                                unsigned short* __restrict__ hout) {
    __shared__ unsigned short hls[4][32][136];
    int lane = threadIdx.x & 63;
    int wave = threadIdx.x >> 6;
    int row0 = blockIdx.x * 128 + wave * 32;
    int lrow = lane & 15;
    int lk = (lane >> 4) << 3;
    unsigned short (*S)[136] = hls[wave];

    short8 a[2][4];
#pragma unroll
    for (int rt = 0; rt < 2; ++rt)
#pragma unroll
        for (int ks = 0; ks < 4; ++ks)
            a[rt][ks] = *(const short8*)(agg + (size_t)(row0 + rt * 16 + lrow) * H + ks * 32 + lk);

#pragma unroll
    for (int chf = 0; chf < 2; ++chf) {
        int c0 = chf * 4;
        fx4 acc[2][4];
#pragma unroll
        for (int ct = 0; ct < 4; ++ct) {
            float v = br[(c0 + ct) * 16 + lrow];
#pragma unroll
            for (int rt = 0; rt < 2; ++rt) acc[rt][ct] = fx4{v, v, v, v};
        }
#pragma unroll
        for (int ks = 0; ks < 4; ++ks)
#pragma unroll
            for (int ct = 0; ct < 4; ++ct) {
                short8 w = *(const short8*)(WTr + ((c0 + ct) * 16 + lrow) * H + ks * 32 + lk);
#pragma unroll
                for (int rt = 0; rt < 2; ++rt)
                    acc[rt][ct] = __builtin_amdgcn_mfma_f32_16x16x32_bf16(a[rt][ks], w, acc[rt][ct], 0, 0, 0);
            }
#pragma unroll
        for (int rt = 0; rt < 2; ++rt)
#pragma unroll
            for (int ct = 0; ct < 4; ++ct)
#pragma unroll
                for (int rg = 0; rg < 4; ++rg)
                    S[rt * 16 + ((lane >> 4) << 2) + rg][(c0 + ct) * 16 + lrow] = f2bf(lrelu(acc[rt][ct][rg]));
    }
#pragma unroll
    for (int step = 0; step < 8; ++step) {
        int cch = step * 64 + lane;
        int r = cch >> 4;
        int off = (cch & 15) * 8;
        int gr = row0 + r;
        if (gr < NN)
            *(uint4*)(hout + (size_t)gr * H + off) = *(const uint4*)&S[r][off];
    }
}

// ---------------- FUSED: h_new = lrelu(agg@Wr+br); q = h_new@Wq+bq; k = h_new@Wk+bk ----------------
__global__ __launch_bounds__(256) void k_rqk_mfma(const unsigned short* __restrict__ agg,
                                                  const unsigned short* __restrict__ WTr,
                                                  const float* __restrict__ br,
                                                  const unsigned short* __restrict__ WTq,
                                                  const float* __restrict__ bq,
                                                  const unsigned short* __restrict__ WTk,
                                                  const float* __restrict__ bk,
                                                  unsigned short* __restrict__ q,
                                                  unsigned short* __restrict__ k) {
    __shared__ unsigned short hls[4][32][136];
    int lane = threadIdx.x & 63;
    int wave = threadIdx.x >> 6;
    int row0 = blockIdx.x * 128 + wave * 32;
    int lrow = lane & 15;
    int lk = (lane >> 4) << 3;
    unsigned short (*S)[136] = hls[wave];

    short8 a[2][4];
#pragma unroll
    for (int rt = 0; rt < 2; ++rt)
#pragma unroll
        for (int ks = 0; ks < 4; ++ks)
            a[rt][ks] = *(const short8*)(agg + (size_t)(row0 + rt * 16 + lrow) * H + ks * 32 + lk);

#pragma unroll
    for (int chf = 0; chf < 2; ++chf) {
        int c0 = chf * 4;
        fx4 acc[2][4];
#pragma unroll
        for (int ct = 0; ct < 4; ++ct) {
            float v = br[(c0 + ct) * 16 + lrow];
#pragma unroll
            for (int rt = 0; rt < 2; ++rt) acc[rt][ct] = fx4{v, v, v, v};
        }
#pragma unroll
        for (int ks = 0; ks < 4; ++ks)
#pragma unroll
            for (int ct = 0; ct < 4; ++ct) {
                short8 w = *(const short8*)(WTr + ((c0 + ct) * 16 + lrow) * H + ks * 32 + lk);
#pragma unroll
                for (int rt = 0; rt < 2; ++rt)
                    acc[rt][ct] = __builtin_amdgcn_mfma_f32_16x16x32_bf16(a[rt][ks], w, acc[rt][ct], 0, 0, 0);
            }
#pragma unroll
        for (int rt = 0; rt < 2; ++rt)
#pragma unroll
            for (int ct = 0; ct < 4; ++ct)
#pragma unroll
                for (int rg = 0; rg < 4; ++rg)
                    S[rt * 16 + ((lane >> 4) << 2) + rg][(c0 + ct) * 16 + lrow] = f2bf(lrelu(acc[rt][ct][rg]));
    }

    short8 a2[2][4];
#pragma unroll
    for (int rt = 0; rt < 2; ++rt)
#pragma unroll
        for (int ks = 0; ks < 4; ++ks)
            a2[rt][ks] = *(const short8*)&S[rt * 16 + lrow][ks * 32 + lk];

#pragma unroll
    for (int pass = 0; pass < 4; ++pass) {
        const unsigned short* W = (pass < 2) ? WTq : WTk;
        const float* b = (pass < 2) ? bq : bk;
        unsigned short* o = (pass < 2) ? q : k;
        int c0 = (pass & 1) * 4;
        fx4 acc[2][4];
#pragma unroll
        for (int ct = 0; ct < 4; ++ct) {
            float v = b[(c0 + ct) * 16 + lrow];
#pragma unroll
            for (int rt = 0; rt < 2; ++rt) acc[rt][ct] = fx4{v, v, v, v};
        }
#pragma unroll
        for (int ks = 0; ks < 4; ++ks)
#pragma unroll
            for (int ct = 0; ct < 4; ++ct) {
                short8 w = *(const short8*)(W + ((c0 + ct) * 16 + lrow) * H + ks * 32 + lk);
#pragma unroll
                for (int rt = 0; rt < 2; ++rt)
                    acc[rt][ct] = __builtin_amdgcn_mfma_f32_16x16x32_bf16(a2[rt][ks], w, acc[rt][ct], 0, 0, 0);
            }
#pragma unroll
        for (int rt = 0; rt < 2; ++rt)
#pragma unroll
            for (int ct = 0; ct < 4; ++ct)
#pragma unroll
                for (int rg = 0; rg < 4; ++rg)
                    S[rt * 16 + ((lane >> 4) << 2) + rg][(c0 + ct) * 16 + lrow] = f2bf(acc[rt][ct][rg]);
#pragma unroll
        for (int step = 0; step < 4; ++step) {
            int cch = step * 64 + lane;
            int r = cch >> 3;
            int off = c0 * 16 + (cch & 7) * 8;
            int gr = row0 + r;
            if (gr < NN)
                *(uint4*)(o + (size_t)gr * H + off) = *(const uint4*)&S[r][off];
        }
    }
}

// ---------------- aggregation: 16 gathers per iter group (4 in flight per lane) ----------------
__global__ __launch_bounds__(256) void k_agg(const unsigned short* __restrict__ q,
                                             const unsigned short* __restrict__ kk,
                                             const int* __restrict__ rowp,
                                             const int* __restrict__ csr_src,
                                             unsigned short* __restrict__ agg) {
    int node = blockIdx.x * 4 + (threadIdx.x >> 6);
    if (node >= NN) return;
    int lane = threadIdx.x & 63;
    int qt = lane >> 4;
    int ql = lane & 15;
    int start = rowp[node];
    int end = rowp[node + 1];

    uint4 qp = *(const uint4*)(q + (size_t)node * H + ql * 8);
    float qv0 = bflo(qp.x), qv1 = bfhi(qp.x), qv2 = bflo(qp.y), qv3 = bfhi(qp.y);
    float qv4 = bflo(qp.z), qv5 = bfhi(qp.z), qv6 = bflo(qp.w), qv7 = bfhi(qp.w);
    float a0 = 0.f, a1 = 0.f, a2 = 0.f, a3 = 0.f, a4 = 0.f, a5 = 0.f, a6 = 0.f, a7 = 0.f;

    for (int base = start; base < end; base += 64) {
        int cnt = end - base;
        if (cnt > 64) cnt = 64;
        int sid = (lane < cnt) ? csr_src[base + lane] : 0;
        int cnt16 = (cnt + 15) & ~15;
        for (int j = 0; j < cnt16; j += 16) {
            int jj0 = j + qt;
            int jj1 = j + 4 + qt;
            int jj2 = j + 8 + qt;
            int jj3 = j + 12 + qt;
            int s0 = __shfl(sid, jj0);
            int s1 = __shfl(sid, jj1);
            int s2 = __shfl(sid, jj2);
            int s3 = __shfl(sid, jj3);
            uint4 kp0 = *(const uint4*)(kk + (size_t)s0 * H + ql * 8);
            uint4 kp1 = *(const uint4*)(kk + (size_t)s1 * H + ql * 8);
            uint4 kp2 = *(const uint4*)(kk + (size_t)s2 * H + ql * 8);
            uint4 kp3 = *(const uint4*)(kk + (size_t)s3 * H + ql * 8);
            if (jj0 < cnt) {
                a0 += lrelu(qv0 + bflo(kp0.x)); a1 += lrelu(qv1 + bfhi(kp0.x));
                a2 += lrelu(qv2 + bflo(kp0.y)); a3 += lrelu(qv3 + bfhi(kp0.y));
                a4 += lrelu(qv4 + bflo(kp0.z)); a5 += lrelu(qv5 + bfhi(kp0.z));
                a6 += lrelu(qv6 + bflo(kp0.w)); a7 += lrelu(qv7 + bfhi(kp0.w));
            }
            if (jj1 < cnt) {
                a0 += lrelu(qv0 + bflo(kp1.x)); a1 += lrelu(qv1 + bfhi(kp1.x));
                a2 += lrelu(qv2 + bflo(kp1.y)); a3 += lrelu(qv3 + bfhi(kp1.y));
                a4 += lrelu(qv4 + bflo(kp1.z)); a5 += lrelu(qv5 + bfhi(kp1.z));
                a6 += lrelu(qv6 + bflo(kp1.w)); a7 += lrelu(qv7 + bfhi(kp1.w));
            }
            if (jj2 < cnt) {
                a0 += lrelu(qv0 + bflo(kp2.x)); a1 += lrelu(qv1 + bfhi(kp2.x));
                a2 += lrelu(qv2 + bflo(kp2.y)); a3 += lrelu(qv3 + bfhi(kp2.y));
                a4 += lrelu(qv4 + bflo(kp2.z)); a5 += lrelu(qv5 + bfhi(kp2.z));
                a6 += lrelu(qv6 + bflo(kp2.w)); a7 += lrelu(qv7 + bfhi(kp2.w));
            }
            if (jj3 < cnt) {
                a0 += lrelu(qv0 + bflo(kp3.x)); a1 += lrelu(qv1 + bfhi(kp3.x));
                a2 += lrelu(qv2 + bflo(kp3.y)); a3 += lrelu(qv3 + bfhi(kp3.y));
                a4 += lrelu(qv4 + bflo(kp3.z)); a5 += lrelu(qv5 + bfhi(kp3.z));
                a6 += lrelu(qv6 + bflo(kp3.w)); a7 += lrelu(qv7 + bfhi(kp3.w));
            }
        }
    }
    a0 += __shfl_xor(a0, 16); a0 += __shfl_xor(a0, 32);
    a1 += __shfl_xor(a1, 16); a1 += __shfl_xor(a1, 32);
    a2 += __shfl_xor(a2, 16); a2 += __shfl_xor(a2, 32);
    a3 += __shfl_xor(a3, 16); a3 += __shfl_xor(a3, 32);
    a4 += __shfl_xor(a4, 16); a4 += __shfl_xor(a4, 32);
    a5 += __shfl_xor(a5, 16); a5 += __shfl_xor(a5, 32);
    a6 += __shfl_xor(a6, 16); a6 += __shfl_xor(a6, 32);
    a7 += __shfl_xor(a7, 16); a7 += __shfl_xor(a7, 32);
    if (qt == 0) {
        uint4 o;
        o.x = (unsigned int)f2bf(a0) | ((unsigned int)f2bf(a1) << 16);
        o.y = (unsigned int)f2bf(a2) | ((unsigned int)f2bf(a3) << 16);
        o.z = (unsigned int)f2bf(a4) | ((unsigned int)f2bf(a5) << 16);
        o.w = (unsigned int)f2bf(a6) | ((unsigned int)f2bf(a7) << 16);
        *(uint4*)(agg + (size_t)node * H + ql * 8) = o;
    }
}

// ---------------- segmented graph pooling ----------------
__global__ __launch_bounds__(256) void k_pool_seg(const unsigned short* __restrict__ h,
                                                  const int* __restrict__ gstart,
                                                  float* __restrict__ hg) {
    int g = blockIdx.x * 4 + (threadIdx.x >> 6);
    if (g >= NG) return;
    int lane = threadIdx.x & 63;
    int s = gstart[g], e = gstart[g + 1];
    float ax = 0.f, ay = 0.f;
    for (int n = s; n < e; ++n) {
        unsigned int hp = *(const unsigned int*)(h + (size_t)n * H + lane * 2);
        ax += bflo(hp);
        ay += bfhi(hp);
    }
    float2 o;
    o.x = ax;
    o.y = ay;
    *(float2*)(hg + (size_t)g * H + lane * 2) = o;
}

// ---------------- MLP head ----------------
__global__ __launch_bounds__(256) void k_mlp1(const float* __restrict__ hg,
                                              const float* __restrict__ W1,
                                              const float* __restrict__ b1,
                                              float* __restrict__ x1) {
    __shared__ float W1s[128 * 64];
    __shared__ float hgs[4 * 128];
    int t = threadIdx.x;
    int g0 = blockIdx.x * 4;
#pragma unroll
    for (int i = 0; i < 32; ++i) W1s[t + i * 256] = W1[t + i * 256];
    for (int i = t; i < 4 * 128; i += 256) hgs[i] = hg[(size_t)g0 * H + i];
    __syncthreads();
    int g = t >> 6, c = t & 63;
    float acc = b1[c];
    const float* row = hgs + g * 128;
    for (int j = 0; j < 128; ++j) acc += row[j] * W1s[j * 64 + c];
    x1[(g0 + g) * 64 + c] = acc;
}

template <int C>
__global__ __launch_bounds__(1024) void k_bnstats(const float* __restrict__ x,
                                                  float* __restrict__ stats) {
    __shared__ float red[1024];
    __shared__ float mus[C];
    int t = threadIdx.x;
    int c = t & (C - 1), rc = t / C;
    const int R = 1024 / C;
    float s = 0.f;
    for (int g = rc; g < NG; g += R) s += x[g * C + c];
    red[t] = s;
    __syncthreads();
    if (t < C) {
        float S = 0.f;
        for (int i = 0; i < R; ++i) S += red[i * C + t];
        float mu = S / NG;
        mus[t] = mu;
        stats[t] = mu;
    }
    __syncthreads();
    float mu = mus[c];
    float s2 = 0.f;
    for (int g = rc; g < NG; g += R) {
        float d = x[g * C + c] - mu;
        s2 += d * d;
    }
    red[t] = s2;
    __syncthreads();
    if (t < C) {
        float Q = 0.f;
        for (int i = 0; i < R; ++i) Q += red[i * C + t];
        stats[C + t] = rsqrtf(Q / NG + 1e-5f);
    }
}

__global__ __launch_bounds__(256) void k_mlp2f(const float* __restrict__ x1,
                                               const float* __restrict__ st,
                                               const float* __restrict__ g1,
                                               const float* __restrict__ be1,
                                               const float* __restrict__ W2,
                                               const float* __restrict__ b2,
                                               float* __restrict__ x2) {
    __shared__ float W2s[64 * 32];
    __shared__ float x1s[8 * 64];
    int t = threadIdx.x;
    int g0 = blockIdx.x * 8;
#pragma unroll
    for (int i = 0; i < 8; ++i) W2s[t + i * 256] = W2[t + i * 256];
#pragma unroll
    for (int i = 0; i < 2; ++i) {
        int idx = t + i * 256;
        int c = idx & 63;
        float v = x1[(size_t)g0 * 64 + idx];
        v = (v - st[c]) * st[64 + c] * g1[c] + be1[c];
        x1s[idx] = lrelu(v);
    }
    __syncthreads();
    int g = t >> 5, c = t & 31;
    float acc = b2[c];
    const float* row = x1s + g * 64;
    for (int j = 0; j < 64; ++j) acc += row[j] * W2s[j * 32 + c];
    x2[(g0 + g) * 32 + c] = acc;
}

__global__ __launch_bounds__(256) void k_mlp3f(const float* __restrict__ x2,
                                               const float* __restrict__ st,
                                               const float* __restrict__ g2,
                                               const float* __restrict__ be2,
                                               const float* __restrict__ W3,
                                               const float* __restrict__ b3,
                                               float* __restrict__ out) {
    int g = blockIdx.x * blockDim.x + threadIdx.x;
    if (g >= NG) return;
    float acc = b3[0];
    for (int j = 0; j < 32; ++j) {
        float v = (x2[g * 32 + j] - st[j]) * st[32 + j] * g2[j] + be2[j];
        acc += lrelu(v) * W3[j];
    }
    out[g] = acc;
}

extern "C" void kernel_launch(void* const* d_in, const int* in_sizes, int n_in,
                              void* d_out, int out_size, void* d_ws, size_t ws_size,
                              hipStream_t stream) {
    const int* nfeats = (const int*)d_in[0];
    const int* src = (const int*)d_in[2];
    const int* dst = (const int*)d_in[3];
    const int* gid = (const int*)d_in[4];
    const float* emb = (const float*)d_in[5];
    const float* Wq = (const float*)d_in[6];
    const float* bq = (const float*)d_in[7];
    const float* Wk = (const float*)d_in[8];
    const float* bk = (const float*)d_in[9];
    const float* Wr = (const float*)d_in[10];
    const float* br = (const float*)d_in[11];
    const float* W1 = (const float*)d_in[12];
    const float* b1 = (const float*)d_in[13];
    const float* g1 = (const float*)d_in[14];
    const float* be1 = (const float*)d_in[15];
    const float* W2 = (const float*)d_in[16];
    const float* b2 = (const float*)d_in[17];
    const float* g2 = (const float*)d_in[18];
    const float* be2 = (const float*)d_in[19];
    const float* W3 = (const float*)d_in[20];
    const float* b3 = (const float*)d_in[21];
    float* out = (float*)d_out;

    size_t nh = (size_t)NP * H;
    unsigned short* P0 = (unsigned short*)d_ws;
    unsigned short* P1 = P0 + nh;
    unsigned short* P2 = P1 + nh;
    unsigned short* WT = P2 + nh;
    float* hg = (float*)(WT + 12 * H * H);
    float* x1 = hg + (size_t)NG * H;
    float* x2 = x1 + (size_t)NG * 64;
    float* st = x2 + (size_t)NG * 32;
    int* cursor = (int*)(st + 2 * 64);
    int* rowp = cursor + NN;
    int* bsum = rowp + NN + 1;
    int* csr_src = bsum + 128;
    int* gstart = csr_src + NE;

    // ---- CSR build + graph boundaries (XCD-partitioned hist/scatter) ----
    hipMemsetAsync(cursor, 0, NN * sizeof(int), stream);
    k_hist<<<NB4 * NCHUNK, 256, 0, stream>>>(dst, cursor);
    k_scan1<<<SCAN_BLOCKS, 1024, 0, stream>>>(cursor, rowp, bsum);
    k_scan2<<<1, 128, 0, stream>>>(bsum);
    k_scan3g<<<SCAN3_BLOCKS + 4, 256, 0, stream>>>(bsum, rowp, cursor, gid, gstart);
    k_scatter<<<NB4 * NCHUNK, 256, 0, stream>>>(src, dst, cursor, csr_src);

    // ---- weight prep ----
    k_wt<<<12, 256, 0, stream>>>(Wq, Wk, Wr, WT);

    const int NB = NP / 128;  // 782
    k_aqk_mfma<<<NB, 256, 0, stream>>>(nfeats, emb, WT + 0 * H * H, bq, WT + 1 * H * H, bk, P1, P2);
    for (int l = 0; l < NLAYER; ++l) {
        k_agg<<<(NN + 3) / 4, 256, 0, stream>>>(P1, P2, rowp, csr_src, P0);
        if (l < NLAYER - 1) {
            k_rqk_mfma<<<NB, 256, 0, stream>>>(P0, WT + (size_t)(l * 3 + 2) * H * H, br + l * H,
                                               WT + (size_t)((l + 1) * 3 + 0) * H * H, bq + (l + 1) * H,
                                               WT + (size_t)((l + 1) * 3 + 1) * H * H, bk + (l + 1) * H,
                                               P1, P2);
        } else {
            k_r_mfma<<<NB, 256, 0, stream>>>(P0, WT + (size_t)(l * 3 + 2) * H * H, br + l * H, P1);
        }
    }

    k_pool_seg<<<(NG + 3) / 4, 256, 0, stream>>>(P1, gstart, hg);

    // ---- MLP head ----
    k_mlp1<<<NG / 4, 256, 0, stream>>>(hg, W1, b1, x1);
    k_bnstats<64><<<1, 1024, 0, stream>>>(x1, st);
    k_mlp2f<<<NG / 8, 256, 0, stream>>>(x1, st, g1, be1, W2, b2, x2);
    k_bnstats<32><<<1, 1024, 0, stream>>>(x2, st);
    k_mlp3f<<<(NG + 255) / 256, 256, 0, stream>>>(x2, st, g2, be2, W3, b3, out);
}